// Round 5
// baseline (219.445 us; speedup 1.0000x reference)
//
#include <hip/hip_runtime.h>
#include <hip/hip_bf16.h>
#include <stdint.h>

#define N_ROWS 4096
#define DIM    2048
#define EPSF   1e-12f

typedef __bf16 bf16x8 __attribute__((ext_vector_type(8)));
typedef float  f32x4  __attribute__((ext_vector_type(4)));

typedef __attribute__((address_space(1))) void gv_t;
typedef __attribute__((address_space(3))) void lv_t;

__device__ __forceinline__ void gload_lds16(const void* g, void* l) {
    // async global->LDS, 16B per lane; LDS dest = wave-uniform base + lane*16
    __builtin_amdgcn_global_load_lds((gv_t*)g, (lv_t*)l, 16, 0, 0);
}

// round-to-nearest-even f32 -> bf16 bits
__device__ __forceinline__ unsigned short f2bf(float f) {
    unsigned u = __float_as_uint(f);
    return (unsigned short)((u + 0x7FFFu + ((u >> 16) & 1u)) >> 16);
}

// ---------------------------------------------------------------------------
// Kernel 1: f32 -> bf16 convert, row sum-of-squares, init per-row atoms.
// One block per row; blocks [0,4096) = modal1, [4096,8192) = modal2.
// ---------------------------------------------------------------------------
__global__ __launch_bounds__(256) void prep_kernel(
    const float* __restrict__ m1, const float* __restrict__ m2,
    unsigned short* __restrict__ abf, unsigned short* __restrict__ bbf,
    float* __restrict__ sq1, float* __restrict__ sq2,
    unsigned* __restrict__ ap_bits, unsigned* __restrict__ an_bits) {
    const int blk = blockIdx.x;
    const bool isB = blk >= N_ROWS;
    const int r = isB ? blk - N_ROWS : blk;
    const float* src = (isB ? m2 : m1) + (size_t)r * DIM;
    unsigned short* dst = (isB ? bbf : abf) + (size_t)r * DIM;
    const int tid = threadIdx.x;

    const float4* s4 = (const float4*)src;        // 2048 f32 = 512 float4
    float4 v0 = s4[tid * 2];
    float4 v1 = s4[tid * 2 + 1];
    float acc = v0.x*v0.x + v0.y*v0.y + v0.z*v0.z + v0.w*v0.w
              + v1.x*v1.x + v1.y*v1.y + v1.z*v1.z + v1.w*v1.w;

    uint4 pk;
    pk.x = (unsigned)f2bf(v0.x) | ((unsigned)f2bf(v0.y) << 16);
    pk.y = (unsigned)f2bf(v0.z) | ((unsigned)f2bf(v0.w) << 16);
    pk.z = (unsigned)f2bf(v1.x) | ((unsigned)f2bf(v1.y) << 16);
    pk.w = (unsigned)f2bf(v1.z) | ((unsigned)f2bf(v1.w) << 16);
    *(uint4*)(dst + tid * 8) = pk;

    // wave64 reduce, then cross-wave via LDS
    for (int s = 32; s > 0; s >>= 1) acc += __shfl_down(acc, s);
    __shared__ float red[4];
    if ((tid & 63) == 0) red[tid >> 6] = acc;
    __syncthreads();
    if (tid == 0) {
        float* sq = isB ? sq2 : sq1;
        sq[r] = red[0] + red[1] + red[2] + red[3];
        if (!isB) {
            ap_bits[r] = 0u;           // max over positive floats: 0.0f = -inf stand-in
            an_bits[r] = 0x7f800000u;  // +inf
        }
    }
}

// ---------------------------------------------------------------------------
// Kernel 2: fused bf16 MFMA GEMM (A·B^T) + distance + masked max/min + atomics.
// 128x128 tile, BK=32, 4 waves (each wave owns a 64x64 quadrant, acc[4][4]).
// ---------------------------------------------------------------------------
__global__ __launch_bounds__(256) void dist_gemm_kernel(
    const unsigned short* __restrict__ A, const unsigned short* __restrict__ B,
    const float* __restrict__ sq1, const float* __restrict__ sq2,
    const int* __restrict__ tgt,
    unsigned* __restrict__ ap_bits, unsigned* __restrict__ an_bits) {
    __shared__ unsigned short As[128 * 32];   // 8 KB
    __shared__ unsigned short Bs[128 * 32];   // 8 KB

    const int tid  = threadIdx.x;
    const int w    = tid >> 6;
    const int lane = tid & 63;
    const int wr   = w >> 1, wc = w & 1;      // wave quadrant (2x2 of 64x64)
    const int l15  = lane & 15, lhi = lane >> 4;
    const int brow = blockIdx.y * 128, bcol = blockIdx.x * 128;

    // staging geometry: chunk = 1024B = 16 rows of 32 bf16; lane l -> row l>>2, k-elem (l&3)*8
    const int srow  = lane >> 2;
    const int skoff = (lane & 3) * 8;
    const int c0 = w, c1 = w + 4;             // each wave stages 2 chunks of A and of B

    f32x4 acc[4][4] = {};

    for (int kt = 0; kt < DIM; kt += 32) {
        const unsigned short* ga0 = A + (size_t)(brow + c0 * 16 + srow) * DIM + kt + skoff;
        gload_lds16(ga0, &As[c0 * 512]);
        const unsigned short* ga1 = A + (size_t)(brow + c1 * 16 + srow) * DIM + kt + skoff;
        gload_lds16(ga1, &As[c1 * 512]);
        const unsigned short* gb0 = B + (size_t)(bcol + c0 * 16 + srow) * DIM + kt + skoff;
        gload_lds16(gb0, &Bs[c0 * 512]);
        const unsigned short* gb1 = B + (size_t)(bcol + c1 * 16 + srow) * DIM + kt + skoff;
        gload_lds16(gb1, &Bs[c1 * 512]);

        __syncthreads();   // drains vmcnt (global_load_lds) + barrier

        bf16x8 af[4], bfr[4];
#pragma unroll
        for (int m = 0; m < 4; ++m)
            af[m] = *(const bf16x8*)&As[(wr * 64 + m * 16 + l15) * 32 + lhi * 8];
#pragma unroll
        for (int n = 0; n < 4; ++n)
            bfr[n] = *(const bf16x8*)&Bs[(wc * 64 + n * 16 + l15) * 32 + lhi * 8];

#pragma unroll
        for (int m = 0; m < 4; ++m)
#pragma unroll
            for (int n = 0; n < 4; ++n)
                acc[m][n] = __builtin_amdgcn_mfma_f32_16x16x32_bf16(af[m], bfr[n], acc[m][n], 0, 0, 0);

        __syncthreads();   // all waves done reading before next-tile overwrite
    }

    // ---- fused epilogue: dist = sqrt(max(s1 + s2 - 2*dot, EPS)); masked max/min ----
    int   tcol[4];
    float s2c[4];
#pragma unroll
    for (int n = 0; n < 4; ++n) {
        int col = bcol + wc * 64 + n * 16 + l15;
        tcol[n] = tgt[col];
        s2c[n]  = sq2[col];
    }
    const float INF = __uint_as_float(0x7f800000u);
#pragma unroll
    for (int m = 0; m < 4; ++m) {
#pragma unroll
        for (int reg = 0; reg < 4; ++reg) {
            // C/D layout (m89-verified): col = lane&15, row = (lane>>4)*4 + reg
            int   row  = brow + wr * 64 + m * 16 + lhi * 4 + reg;
            int   trow = tgt[row];
            float s1   = sq1[row];
            float pmax = 0.0f;   // dist > 0 always, so 0 works as -inf
            float nmin = INF;
#pragma unroll
            for (int n = 0; n < 4; ++n) {
                float d2 = s1 + s2c[n] - 2.0f * acc[m][n][reg];
                float dd = sqrtf(fmaxf(d2, EPSF));
                if (trow == tcol[n]) pmax = fmaxf(pmax, dd);
                else                 nmin = fminf(nmin, dd);
            }
            // reduce across the 16 lanes sharing this row
#pragma unroll
            for (int s = 1; s < 16; s <<= 1) {
                pmax = fmaxf(pmax, __shfl_xor(pmax, s));
                nmin = fminf(nmin, __shfl_xor(nmin, s));
            }
            if (l15 == 0) {
                // positive-float bits are monotone under unsigned compare
                atomicMax(&ap_bits[row], __float_as_uint(pmax));
                atomicMin(&an_bits[row], __float_as_uint(nmin));
            }
        }
    }
}

// ---------------------------------------------------------------------------
// Kernel 3: loss = mean(relu(ap - an + margin)); prec = mean(an > ap)
// ---------------------------------------------------------------------------
__global__ __launch_bounds__(256) void finalize_kernel(
    const unsigned* __restrict__ ap_bits, const unsigned* __restrict__ an_bits,
    const float* __restrict__ marginp, float* __restrict__ out) {
    const int tid = threadIdx.x;
    const float margin = marginp[0];
    float ls = 0.f, ps = 0.f;
    for (int i = tid; i < N_ROWS; i += 256) {
        float a = __uint_as_float(ap_bits[i]);
        float b = __uint_as_float(an_bits[i]);
        ls += fmaxf(a - b + margin, 0.0f);
        ps += (b > a) ? 1.0f : 0.0f;
    }
    for (int s = 32; s > 0; s >>= 1) {
        ls += __shfl_down(ls, s);
        ps += __shfl_down(ps, s);
    }
    __shared__ float sl[4], sp[4];
    if ((tid & 63) == 0) { sl[tid >> 6] = ls; sp[tid >> 6] = ps; }
    __syncthreads();
    if (tid == 0) {
        ls = sl[0] + sl[1] + sl[2] + sl[3];
        ps = sp[0] + sp[1] + sp[2] + sp[3];
        out[0] = ls / (float)N_ROWS;
        out[1] = ps / (float)N_ROWS;
    }
}

// ---------------------------------------------------------------------------
extern "C" void kernel_launch(void* const* d_in, const int* in_sizes, int n_in,
                              void* d_out, int out_size, void* d_ws, size_t ws_size,
                              hipStream_t stream) {
    const float* m1  = (const float*)d_in[0];
    const float* m2  = (const float*)d_in[1];
    const int*   tgt = (const int*)d_in[2];
    const float* mrg = (const float*)d_in[3];

    char* ws = (char*)d_ws;
    unsigned short* abf = (unsigned short*)ws;                         // 16 MB bf16 modal1
    unsigned short* bbf = (unsigned short*)(ws + 16777216);            // 16 MB bf16 modal2
    float*    sq1 = (float*)(ws + 33554432);                           // 16 KB
    float*    sq2 = (float*)(ws + 33554432 + 16384);                   // 16 KB
    unsigned* ap  = (unsigned*)(ws + 33554432 + 32768);                // 16 KB
    unsigned* an  = (unsigned*)(ws + 33554432 + 49152);                // 16 KB

    float* outp = (float*)d_out;

    prep_kernel<<<2 * N_ROWS, 256, 0, stream>>>(m1, m2, abf, bbf, sq1, sq2, ap, an);
    dim3 grid(N_ROWS / 128, N_ROWS / 128);
    dist_gemm_kernel<<<grid, 256, 0, stream>>>(abf, bbf, sq1, sq2, tgt, ap, an);
    finalize_kernel<<<1, 256, 0, stream>>>(ap, an, mrg, outp);
}